// Round 11
// baseline (86.521 us; speedup 1.0000x reference)
//
#include <hip/hip_runtime.h>
#include <hip/hip_bf16.h>
#include <cstdint>

typedef unsigned short u16;
typedef __attribute__((ext_vector_type(8))) short short8;   // 8 bf16 = 4 VGPR
typedef __attribute__((ext_vector_type(4))) short short4v;  // 4 bf16 = 8B
typedef __attribute__((ext_vector_type(4))) float f32x4;

#define MFMA16(a, b, c) __builtin_amdgcn_mfma_f32_16x16x32_bf16((a), (b), (c), 0, 0, 0)

constexpr int Bn   = 16;
constexpr int Tn   = 2048;
constexpr int Cn   = 384;
constexpr int Hn   = 64;
constexpr long NTOK = (long)Bn * Tn;          // 32768
constexpr long NELT = NTOK * Hn;              // 2,097,152
constexpr int SPLITS = 4;                     // flash split-K factor
constexpr int NT_PER = 32 / SPLITS;           // KV tiles per block

// Q pre-scale: (1/sqrt(64)) * log2(e), so attention uses bare exp2
#define QSCALE 0.18033688011112042f

// f32 -> bf16 round-to-nearest-even
__device__ __forceinline__ u16 f2bf(float f) {
  union { float f; uint32_t u; } c; c.f = f;
  uint32_t u = c.u;
  return (u16)((u + 0x7fffu + ((u >> 16) & 1u)) >> 16);
}

// pack 2 f32 -> 2 bf16 in one u32 (RNE), gfx950 v_cvt_pk_bf16_f32
__device__ __forceinline__ uint32_t pkbf(float a, float b) {
  uint32_t d;
  asm("v_cvt_pk_bf16_f32 %0, %1, %2" : "=v"(d) : "v"(a), "v"(b));
  return d;
}

// async global->LDS, 16B per lane. LDS dest = wave-uniform base + lane*16.
__device__ __forceinline__ void gl16(const u16* g, const u16* l) {
  __builtin_amdgcn_global_load_lds(
      (const __attribute__((address_space(1))) void*)g,
      (__attribute__((address_space(3))) void*)l, 16, 0, 0);
}

// ---------------------------------------------------------------------------
// Kernel 0: W pre-transpose.  W[384][64] f32 (x3) -> WT[3][64][384] bf16.
// Grid: 18 blocks (3 m x 6 k-chunks) x 256 thr; LDS tile transpose.
// ---------------------------------------------------------------------------
__global__ __launch_bounds__(256) void wtrans(
    const float* __restrict__ Wq, const float* __restrict__ Wk,
    const float* __restrict__ Wv, u16* __restrict__ wtd)
{
  __shared__ u16 tile[64][65];
  const int m  = blockIdx.x / 6;
  const int kc = blockIdx.x % 6;
  const float* W = (m == 0) ? Wq : (m == 1) ? Wk : Wv;
  const int t = threadIdx.x;

  // load W[kc*64+kr][seg*16 .. +16], convert, store LDS [kr][h]
  {
    const int kr = t >> 2, seg = t & 3;
    const float* src = W + (size_t)(kc * 64 + kr) * Hn + seg * 16;
    #pragma unroll
    for (int j = 0; j < 4; ++j) {
      const float4 f = *reinterpret_cast<const float4*>(src + j * 4);
      u16* p = &tile[kr][seg * 16 + j * 4];
      p[0] = f2bf(f.x); p[1] = f2bf(f.y); p[2] = f2bf(f.z); p[3] = f2bf(f.w);
    }
  }
  __syncthreads();
  // write WT[m][hr][kc*64 + seg*16 .. +16] (coalesced 32B per thread)
  {
    const int hr = t >> 2, seg = t & 3;
    union { short8 s; u16 u[8]; } o0, o1;
    #pragma unroll
    for (int j = 0; j < 8; ++j) o0.u[j] = tile[seg * 16 + j][hr];
    #pragma unroll
    for (int j = 0; j < 8; ++j) o1.u[j] = tile[seg * 16 + 8 + j][hr];
    u16* dst = wtd + ((size_t)m * 64 + hr) * Cn + kc * 64 + seg * 16;
    *reinterpret_cast<short8*>(dst)     = o0.s;
    *reinterpret_cast<short8*>(dst + 8) = o1.s;
  }
}

// ---------------------------------------------------------------------------
// Kernel 1: QKV projection — LDS-free, barrier-free, 1 wave per block.
// Grid: 2048 blocks x 64 thr; each wave computes 16 token-rows x 64 cols x3.
// A-frags direct from x (f32->bf16 via cvt_pk); B-frags direct from
// L2-resident pre-transposed WT bf16.
// ---------------------------------------------------------------------------
__global__ __launch_bounds__(64) void qkv_proj(
    const float* __restrict__ x, const u16* __restrict__ wtd,
    const float* __restrict__ bq, const float* __restrict__ bk,
    const float* __restrict__ bv,
    u16* __restrict__ oq, u16* __restrict__ ok, u16* __restrict__ ovt)
{
  const int lane = threadIdx.x;
  const int l15  = lane & 15;
  const int lh   = lane >> 4;
  const long r0  = (long)blockIdx.x * 16;

  f32x4 acc[3][4];
  #pragma unroll
  for (int m = 0; m < 3; ++m)
    #pragma unroll
    for (int n = 0; n < 4; ++n) acc[m][n] = f32x4{0.f, 0.f, 0.f, 0.f};

  const float* xrow = x + (r0 + l15) * Cn;

  #pragma unroll
  for (int kc = 0; kc < 6; ++kc) {
    // A-frags: x[r0+l15][kc*64 + ks*32 + lh*8 .. +8]
    union { short8 s8; uint32_t u[4]; } a[2];
    #pragma unroll
    for (int ks = 0; ks < 2; ++ks) {
      const float* p = xrow + kc * 64 + ks * 32 + lh * 8;
      const float4 f0 = *reinterpret_cast<const float4*>(p);
      const float4 f1 = *reinterpret_cast<const float4*>(p + 4);
      a[ks].u[0] = pkbf(f0.x, f0.y); a[ks].u[1] = pkbf(f0.z, f0.w);
      a[ks].u[2] = pkbf(f1.x, f1.y); a[ks].u[3] = pkbf(f1.z, f1.w);
    }
    #pragma unroll
    for (int m = 0; m < 3; ++m)
      #pragma unroll
      for (int n = 0; n < 4; ++n) {
        const u16* wrow = wtd + ((size_t)m * 64 + n * 16 + l15) * Cn + kc * 64;
        const short8 b0 = *reinterpret_cast<const short8*>(wrow + lh * 8);
        acc[m][n] = MFMA16(a[0].s8, b0, acc[m][n]);
        const short8 b1 = *reinterpret_cast<const short8*>(wrow + 32 + lh * 8);
        acc[m][n] = MFMA16(a[1].s8, b1, acc[m][n]);
      }
  }

  // epilogue: q (scaled) and k row-major
  {
    const float* bias[2] = {bq, bk};
    u16*         dst[2]  = {oq, ok};
    const float  scl[2]  = {QSCALE, 1.0f};
    #pragma unroll
    for (int m = 0; m < 2; ++m) {
      #pragma unroll
      for (int n = 0; n < 4; ++n) {
        int col = n * 16 + l15;
        float bb = bias[m][col];
        #pragma unroll
        for (int r = 0; r < 4; ++r) {
          int row = lh * 4 + r;
          dst[m][(r0 + row) * Hn + col] = f2bf((acc[m][n][r] + bb) * scl[m]);
        }
      }
    }
  }
  // v: TRANSPOSED [b][h][t]; lane packs its 4 consecutive tokens into 8B
  {
    const long g    = r0 + lh * 4;
    const long bidx = g >> 11;
    const long tloc = g & 2047;
    #pragma unroll
    for (int n = 0; n < 4; ++n) {
      int col = n * 16 + l15;
      float bb = bv[col];
      short4v pk;
      #pragma unroll
      for (int r = 0; r < 4; ++r) pk[r] = (short)f2bf(acc[2][n][r] + bb);
      *reinterpret_cast<short4v*>(ovt + (bidx * Hn + col) * Tn + tloc) = pk;
    }
  }
}

// ---------------------------------------------------------------------------
// Kernel 2: flash attention, swapped-QK in-register softmax, SPLIT-K x4.
// Max-free softmax => partials combine by plain addition.
// Grid: 2048 blocks (4 splits x 16 b x 32 qt) x 256 thr; 8 KV tiles each.
// 32 KB LDS/block -> 5 blocks/CU (LDS-capped) -> 20 waves/CU.
// ---------------------------------------------------------------------------
__global__ __launch_bounds__(256) void flash_attn(
    const u16* __restrict__ q, const u16* __restrict__ k,
    const u16* __restrict__ vt, float* __restrict__ opart,
    float* __restrict__ lpart)
{
  __shared__ u16 kbuf[2][64 * 64];   // K tile [key][h], granule-XOR swizzled
  __shared__ u16 vbuf[2][64 * 64];   // V^T tile [h][kslot], pi-permuted + swizzled

  const int t    = threadIdx.x;
  const int lane = t & 63;
  const int w    = t >> 6;
  const int l15  = lane & 15;
  const int lh   = lane >> 4;
  // XCD swizzle (bit permutation, bijective; 2048 % 8 == 0)
  const int swz_id = ((blockIdx.x & 7) << 8) | (blockIdx.x >> 3);
  const int qt    = swz_id & 31;
  const int split = (swz_id >> 5) & (SPLITS - 1);
  const int b     = swz_id >> 7;
  const long rowbase = (long)b * Tn + qt * 64;
  const int it0 = split * NT_PER, it1 = it0 + NT_PER;

  // Q fragments (loop-invariant, direct from global); MFMA B-operand
  short8 aq[2];
  {
    const u16* qrow = q + (rowbase + w * 16 + l15) * Hn;
    aq[0] = *reinterpret_cast<const short8*>(qrow + lh * 8);
    aq[1] = *reinterpret_cast<const short8*>(qrow + 32 + lh * 8);
  }

  // O^T accumulators: o[m][r] = O[q=l15][h=16m+4lh+r]
  f32x4 o[4];
  #pragma unroll
  for (int m = 0; m < 4; ++m) o[m] = f32x4{0.f, 0.f, 0.f, 0.f};
  float lacc = 0.f;

  const u16* kb_g = k  + (long)b * Tn * Hn;
  const u16* vb_g = vt + (long)b * Hn * Tn;

  // K staging: 16B granule-XOR (LDS slot (r,c) <- global granule (r, c^(r&7)))
  const int g0 = t, g1 = 256 + t;
  const int r0g = g0 >> 3, c0g = g0 & 7;
  const int r1g = g1 >> 3, c1g = g1 & 7;
  const int ksrc0 = r0g * Hn + ((c0g ^ (r0g & 7)) << 3);
  const int ksrc1 = r1g * Hn + ((c1g ^ (r1g & 7)) << 3);
  const int wb0 = w * 64 * 8;
  const int wb1 = wb0 + 256 * 8;

  // V staging (reg-staged, pi + XOR folded into write addresses)
  const int vrow = w * 16 + (lane >> 2);
  const int vc   = lane & 3;
  const long vgbase = (long)vrow * Tn + vc * 16;
  const int vs_ = vrow & 7;

  // fragment-read swizzle
  const int swz  = l15 & 7;
  const int cks0 = ((0 * 4 + lh) ^ swz) << 3;
  const int cks1 = ((1 * 4 + lh) ^ swz) << 3;
  const int rfr  = l15 * 64;

  int cur = 0;

  // prologue: stage tile it0
  {
    const u16* kt = kb_g + (long)it0 * 64 * Hn;
    gl16(kt + ksrc0, &kbuf[0][wb0]);
    gl16(kt + ksrc1, &kbuf[0][wb1]);
    const short8 v0 = *reinterpret_cast<const short8*>(vb_g + vgbase + it0 * 64);
    const short8 v1 = *reinterpret_cast<const short8*>(vb_g + vgbase + it0 * 64 + 8);
    u16* vdst = &vbuf[0][0] + vrow * 64;
    const int gb = (vc >> 1) * 4, off8 = (vc & 1) * 4;
    *reinterpret_cast<short4v*>(vdst + (((gb + 0) ^ vs_) << 3) + off8) = short4v{v0[0], v0[1], v0[2], v0[3]};
    *reinterpret_cast<short4v*>(vdst + (((gb + 1) ^ vs_) << 3) + off8) = short4v{v0[4], v0[5], v0[6], v0[7]};
    *reinterpret_cast<short4v*>(vdst + (((gb + 2) ^ vs_) << 3) + off8) = short4v{v1[0], v1[1], v1[2], v1[3]};
    *reinterpret_cast<short4v*>(vdst + (((gb + 3) ^ vs_) << 3) + off8) = short4v{v1[4], v1[5], v1[6], v1[7]};
  }
  __syncthreads();

  for (int it = it0; it < it1; ++it) {
    // prefetch tile it+1: K -> LDS (async), V -> regs (written after PV)
    short8 nv0, nv1;
    const bool pf = (it + 1 < it1);
    if (pf) {
      const u16* kt = kb_g + (long)(it + 1) * 64 * Hn;
      gl16(kt + ksrc0, &kbuf[cur ^ 1][wb0]);
      gl16(kt + ksrc1, &kbuf[cur ^ 1][wb1]);
      nv0 = *reinterpret_cast<const short8*>(vb_g + vgbase + (it + 1) * 64);
      nv1 = *reinterpret_cast<const short8*>(vb_g + vgbase + (it + 1) * 64 + 8);
    }

    const u16* kc  = &kbuf[cur][0];
    const u16* vcb = &vbuf[cur][0];

    // S^T = K Q^T
    f32x4 s[4];
    #pragma unroll
    for (int n = 0; n < 4; ++n) s[n] = f32x4{0.f, 0.f, 0.f, 0.f};
    #pragma unroll
    for (int n = 0; n < 4; ++n) {
      const short8 ak0 = *reinterpret_cast<const short8*>(&kc[n * 1024 + rfr + cks0]);
      s[n] = MFMA16(ak0, aq[0], s[n]);
      const short8 ak1 = *reinterpret_cast<const short8*>(&kc[n * 1024 + rfr + cks1]);
      s[n] = MFMA16(ak1, aq[1], s[n]);
    }

    // P = exp2(S) in-register (max-free)
    #pragma unroll
    for (int n = 0; n < 4; ++n)
      #pragma unroll
      for (int r = 0; r < 4; ++r)
        s[n][r] = __builtin_amdgcn_exp2f(s[n][r]);

    // row-sum partial
    {
      float t0 = (s[0][0] + s[0][1]) + (s[0][2] + s[0][3]);
      float t1 = (s[1][0] + s[1][1]) + (s[1][2] + s[1][3]);
      float t2 = (s[2][0] + s[2][1]) + (s[2][2] + s[2][3]);
      float t3 = (s[3][0] + s[3][1]) + (s[3][2] + s[3][3]);
      lacc += (t0 + t1) + (t2 + t3);
    }

    // PV B-frags: lane-local thanks to pi permutation
    union { short8 s8; uint32_t u[4]; } B0, B1;
    B0.u[0] = pkbf(s[0][0], s[0][1]); B0.u[1] = pkbf(s[0][2], s[0][3]);
    B0.u[2] = pkbf(s[1][0], s[1][1]); B0.u[3] = pkbf(s[1][2], s[1][3]);
    B1.u[0] = pkbf(s[2][0], s[2][1]); B1.u[1] = pkbf(s[2][2], s[2][3]);
    B1.u[2] = pkbf(s[3][0], s[3][1]); B1.u[3] = pkbf(s[3][2], s[3][3]);

    // O^T += V'^T P^T
    #pragma unroll
    for (int m = 0; m < 4; ++m) {
      const short8 av0 = *reinterpret_cast<const short8*>(&vcb[m * 1024 + rfr + cks0]);
      o[m] = MFMA16(av0, B0.s8, o[m]);
      const short8 av1 = *reinterpret_cast<const short8*>(&vcb[m * 1024 + rfr + cks1]);
      o[m] = MFMA16(av1, B1.s8, o[m]);
    }

    // write prefetched V into the other buffer (pi + XOR dest)
    if (pf) {
      u16* vdst = &vbuf[cur ^ 1][0] + vrow * 64;
      const int gb = (vc >> 1) * 4, off8 = (vc & 1) * 4;
      *reinterpret_cast<short4v*>(vdst + (((gb + 0) ^ vs_) << 3) + off8) = short4v{nv0[0], nv0[1], nv0[2], nv0[3]};
      *reinterpret_cast<short4v*>(vdst + (((gb + 1) ^ vs_) << 3) + off8) = short4v{nv0[4], nv0[5], nv0[6], nv0[7]};
      *reinterpret_cast<short4v*>(vdst + (((gb + 2) ^ vs_) << 3) + off8) = short4v{nv1[0], nv1[1], nv1[2], nv1[3]};
      *reinterpret_cast<short4v*>(vdst + (((gb + 3) ^ vs_) << 3) + off8) = short4v{nv1[4], nv1[5], nv1[6], nv1[7]};
    }

    __syncthreads();
    cur ^= 1;
  }

  // epilogue: write UNNORMALIZED partial O + row-sum l
  float tot = lacc;
  tot += __shfl_xor(tot, 16);
  tot += __shfl_xor(tot, 32);
  const long qrow = rowbase + w * 16 + l15;
  float* od = opart + ((long)split * NELT) + qrow * Hn;
  #pragma unroll
  for (int m = 0; m < 4; ++m) {
    float4 vv;
    vv.x = o[m][0]; vv.y = o[m][1]; vv.z = o[m][2]; vv.w = o[m][3];
    *reinterpret_cast<float4*>(od + m * 16 + lh * 4) = vv;
  }
  if (lh == 0) lpart[(long)split * NTOK + qrow] = tot;
}

// ---------------------------------------------------------------------------
// Kernel 3: combine split-K partials: out = (sum O_s) / (sum l_s)
// ---------------------------------------------------------------------------
__global__ __launch_bounds__(256) void combine(
    const float* __restrict__ op, const float* __restrict__ lp,
    float* __restrict__ out)
{
  const long idx  = (long)blockIdx.x * 256 + threadIdx.x;
  const long base = idx * 4;
  const long row  = base >> 6;
  float4 acc = *reinterpret_cast<const float4*>(op + base);
  float lsum = lp[row];
  #pragma unroll
  for (int s = 1; s < SPLITS; ++s) {
    const float4 c = *reinterpret_cast<const float4*>(op + s * NELT + base);
    acc.x += c.x; acc.y += c.y; acc.z += c.z; acc.w += c.w;
    lsum += lp[s * NTOK + row];
  }
  const float linv = 1.0f / lsum;
  float4 r;
  r.x = acc.x * linv; r.y = acc.y * linv; r.z = acc.z * linv; r.w = acc.w * linv;
  *reinterpret_cast<float4*>(out + base) = r;
}

// ---------------------------------------------------------------------------
extern "C" void kernel_launch(void* const* d_in, const int* in_sizes, int n_in,
                              void* d_out, int out_size, void* d_ws, size_t ws_size,
                              hipStream_t stream) {
  const float* x  = (const float*)d_in[0];
  const float* Wq = (const float*)d_in[1];
  const float* bq = (const float*)d_in[2];
  const float* Wk = (const float*)d_in[3];
  const float* bk = (const float*)d_in[4];
  const float* Wv = (const float*)d_in[5];
  const float* bv = (const float*)d_in[6];
  float* out = (float*)d_out;

  u16* qs  = (u16*)d_ws;                         // [32768][64] bf16, pre-scaled
  u16* ks  = qs + NELT;                          // [32768][64] bf16
  u16* vs  = ks + NELT;                          // V^T [16][64][2048] bf16
  u16* wtd = vs + NELT;                          // WT [3][64][384] bf16
  float* op = (float*)(wtd + 3 * 64 * Cn);       // O partials [SPLITS][32768][64]
  float* lp = op + (long)SPLITS * NELT;          // l partials [SPLITS][32768]

  const int FLASH_BLOCKS = Bn * 32 * SPLITS;     // 16 b x 32 qt x 4 splits = 2048

  hipLaunchKernelGGL(wtrans, dim3(18), dim3(256), 0, stream, Wq, Wk, Wv, wtd);
  hipLaunchKernelGGL(qkv_proj, dim3((int)(NTOK / 16)), dim3(64), 0, stream,
                     x, wtd, bq, bk, bv, qs, ks, vs);
  hipLaunchKernelGGL(flash_attn, dim3(FLASH_BLOCKS), dim3(256), 0, stream,
                     qs, ks, vs, op, lp);
  hipLaunchKernelGGL(combine, dim3((int)(NELT / 4 / 256)), dim3(256), 0, stream,
                     op, lp, out);
}

// Round 12
// 72.777 us; speedup vs baseline: 1.1889x; 1.1889x over previous
//
#include <hip/hip_runtime.h>
#include <hip/hip_bf16.h>
#include <cstdint>

typedef unsigned short u16;
typedef __attribute__((ext_vector_type(8))) short short8;   // 8 bf16 = 4 VGPR
typedef __attribute__((ext_vector_type(4))) short short4v;  // 4 bf16 = 8B
typedef __attribute__((ext_vector_type(4))) float f32x4;

#define MFMA16(a, b, c) __builtin_amdgcn_mfma_f32_16x16x32_bf16((a), (b), (c), 0, 0, 0)

constexpr int Bn   = 16;
constexpr int Tn   = 2048;
constexpr int Cn   = 384;
constexpr int Hn   = 64;
constexpr int WPAD = 72;                      // 64+8 (2-way LDS reads: free)
constexpr long NTOK = (long)Bn * Tn;          // 32768
constexpr long NELT = NTOK * Hn;              // 2,097,152
constexpr int SPLITS = 4;                     // flash split-K factor
constexpr int NT_PER = 32 / SPLITS;           // KV tiles per block

// Q pre-scale: (1/sqrt(64)) * log2(e), so attention uses bare exp2
#define QSCALE 0.18033688011112042f

// f32 -> bf16 round-to-nearest-even
__device__ __forceinline__ u16 f2bf(float f) {
  union { float f; uint32_t u; } c; c.f = f;
  uint32_t u = c.u;
  return (u16)((u + 0x7fffu + ((u >> 16) & 1u)) >> 16);
}

// pack 2 f32 -> 2 bf16 in one u32 (RNE), gfx950 v_cvt_pk_bf16_f32
__device__ __forceinline__ uint32_t pkbf(float a, float b) {
  uint32_t d;
  asm("v_cvt_pk_bf16_f32 %0, %1, %2" : "=v"(d) : "v"(a), "v"(b));
  return d;
}

// async global->LDS, 16B per lane. LDS dest = wave-uniform base + lane*16.
__device__ __forceinline__ void gl16(const u16* g, const u16* l) {
  __builtin_amdgcn_global_load_lds(
      (const __attribute__((address_space(1))) void*)g,
      (__attribute__((address_space(3))) void*)l, 16, 0, 0);
}

// ---------------------------------------------------------------------------
// Kernel 0: W pre-transpose.  W[384][64] f32 (x3) -> WT[3][64][384] bf16.
// ---------------------------------------------------------------------------
__global__ __launch_bounds__(256) void wtrans(
    const float* __restrict__ Wq, const float* __restrict__ Wk,
    const float* __restrict__ Wv, u16* __restrict__ wtd)
{
  __shared__ u16 tile[64][65];
  const int m  = blockIdx.x / 6;
  const int kc = blockIdx.x % 6;
  const float* W = (m == 0) ? Wq : (m == 1) ? Wk : Wv;
  const int t = threadIdx.x;

  {
    const int kr = t >> 2, seg = t & 3;
    const float* src = W + (size_t)(kc * 64 + kr) * Hn + seg * 16;
    #pragma unroll
    for (int j = 0; j < 4; ++j) {
      const float4 f = *reinterpret_cast<const float4*>(src + j * 4);
      u16* p = &tile[kr][seg * 16 + j * 4];
      p[0] = f2bf(f.x); p[1] = f2bf(f.y); p[2] = f2bf(f.z); p[3] = f2bf(f.w);
    }
  }
  __syncthreads();
  {
    const int hr = t >> 2, seg = t & 3;
    union { short8 s; u16 u[8]; } o0, o1;
    #pragma unroll
    for (int j = 0; j < 8; ++j) o0.u[j] = tile[seg * 16 + j][hr];
    #pragma unroll
    for (int j = 0; j < 8; ++j) o1.u[j] = tile[seg * 16 + 8 + j][hr];
    u16* dst = wtd + ((size_t)m * 64 + hr) * Cn + kc * 64 + seg * 16;
    *reinterpret_cast<short8*>(dst)     = o0.s;
    *reinterpret_cast<short8*>(dst + 8) = o1.s;
  }
}

// ---------------------------------------------------------------------------
// Kernel 1: QKV projection.  W staged in LDS from bf16 WT (cheap vector
// copies); x A-frags hoisted to registers up-front (no x LDS round-trip).
// Grid: 512 blocks x 256 thr (4 waves x 16 rows); LDS 27.6 KB -> 5 blocks/CU.
// ---------------------------------------------------------------------------
__global__ __launch_bounds__(256) void qkv_proj(
    const float* __restrict__ x, const u16* __restrict__ wtd,
    const float* __restrict__ bq, const float* __restrict__ bk,
    const float* __restrict__ bv,
    u16* __restrict__ oq, u16* __restrict__ ok, u16* __restrict__ ovt)
{
  __shared__ u16 wt[3][Hn * WPAD];   // W k-chunk, transposed [m][h][k] (27.6 KB)

  const int t    = threadIdx.x;
  const int lane = t & 63;
  const int w    = t >> 6;
  const int l15  = lane & 15;
  const int lh   = lane >> 4;
  const long r0  = (long)blockIdx.x * 64;

  // ---- hoist ALL x A-frags to regs (one pass, coalesced, pre-barrier) ----
  union { short8 s8; uint32_t u[4]; } a[6][2];
  {
    const float* xrow = x + (r0 + w * 16 + l15) * Cn;
    #pragma unroll
    for (int kc = 0; kc < 6; ++kc)
      #pragma unroll
      for (int ks = 0; ks < 2; ++ks) {
        const float* p = xrow + kc * 64 + ks * 32 + lh * 8;
        const float4 f0 = *reinterpret_cast<const float4*>(p);
        const float4 f1 = *reinterpret_cast<const float4*>(p + 4);
        a[kc][ks].u[0] = pkbf(f0.x, f0.y); a[kc][ks].u[1] = pkbf(f0.z, f0.w);
        a[kc][ks].u[2] = pkbf(f1.x, f1.y); a[kc][ks].u[3] = pkbf(f1.z, f1.w);
      }
  }

  f32x4 acc[3][4];
  #pragma unroll
  for (int m = 0; m < 3; ++m)
    #pragma unroll
    for (int n = 0; n < 4; ++n) acc[m][n] = f32x4{0.f, 0.f, 0.f, 0.f};

  for (int kc = 0; kc < 6; ++kc) {
    __syncthreads();   // wt safe to overwrite
    // stage WT chunk: 1536 granules of 16B, coalesced
    #pragma unroll
    for (int i = 0; i < 6; ++i) {
      const int g  = t + i * 256;
      const int c8 = g & 7, h = (g >> 3) & 63, m = g >> 9;
      *reinterpret_cast<short8*>(&wt[m][h * WPAD + c8 * 8]) =
          *reinterpret_cast<const short8*>(
              wtd + ((size_t)m * 64 + h) * Cn + kc * 64 + c8 * 8);
    }
    __syncthreads();

    #pragma unroll
    for (int ks = 0; ks < 2; ++ks)
      #pragma unroll
      for (int m = 0; m < 3; ++m)
        #pragma unroll
        for (int n = 0; n < 4; ++n) {
          const short8 bfr = *reinterpret_cast<const short8*>(
              &wt[m][(n * 16 + l15) * WPAD + ks * 32 + lh * 8]);
          acc[m][n] = MFMA16(a[kc][ks].s8, bfr, acc[m][n]);
        }
  }

  // epilogue: q (scaled) and k row-major
  {
    const float* bias[2] = {bq, bk};
    u16*         dst[2]  = {oq, ok};
    const float  scl[2]  = {QSCALE, 1.0f};
    #pragma unroll
    for (int m = 0; m < 2; ++m) {
      #pragma unroll
      for (int n = 0; n < 4; ++n) {
        int col = n * 16 + l15;
        float bb = bias[m][col];
        #pragma unroll
        for (int r = 0; r < 4; ++r) {
          int row = lh * 4 + r;
          dst[m][(r0 + w * 16 + row) * Hn + col] = f2bf((acc[m][n][r] + bb) * scl[m]);
        }
      }
    }
  }
  // v: TRANSPOSED [b][h][t]
  {
    const long g    = r0 + w * 16 + lh * 4;
    const long bidx = g >> 11;
    const long tloc = g & 2047;
    #pragma unroll
    for (int n = 0; n < 4; ++n) {
      int col = n * 16 + l15;
      float bb = bv[col];
      short4v pk;
      #pragma unroll
      for (int r = 0; r < 4; ++r) pk[r] = (short)f2bf(acc[2][n][r] + bb);
      *reinterpret_cast<short4v*>(ovt + (bidx * Hn + col) * Tn + tloc) = pk;
    }
  }
}

// ---------------------------------------------------------------------------
// Kernel 2: flash attention, swapped-QK in-register softmax, SPLIT-K x4.
// (unchanged from R11, grid 2048)
// ---------------------------------------------------------------------------
__global__ __launch_bounds__(256) void flash_attn(
    const u16* __restrict__ q, const u16* __restrict__ k,
    const u16* __restrict__ vt, float* __restrict__ opart,
    float* __restrict__ lpart)
{
  __shared__ u16 kbuf[2][64 * 64];
  __shared__ u16 vbuf[2][64 * 64];

  const int t    = threadIdx.x;
  const int lane = t & 63;
  const int w    = t >> 6;
  const int l15  = lane & 15;
  const int lh   = lane >> 4;
  const int swz_id = ((blockIdx.x & 7) << 8) | (blockIdx.x >> 3);
  const int qt    = swz_id & 31;
  const int split = (swz_id >> 5) & (SPLITS - 1);
  const int b     = swz_id >> 7;
  const long rowbase = (long)b * Tn + qt * 64;
  const int it0 = split * NT_PER, it1 = it0 + NT_PER;

  short8 aq[2];
  {
    const u16* qrow = q + (rowbase + w * 16 + l15) * Hn;
    aq[0] = *reinterpret_cast<const short8*>(qrow + lh * 8);
    aq[1] = *reinterpret_cast<const short8*>(qrow + 32 + lh * 8);
  }

  f32x4 o[4];
  #pragma unroll
  for (int m = 0; m < 4; ++m) o[m] = f32x4{0.f, 0.f, 0.f, 0.f};
  float lacc = 0.f;

  const u16* kb_g = k  + (long)b * Tn * Hn;
  const u16* vb_g = vt + (long)b * Hn * Tn;

  const int g0 = t, g1 = 256 + t;
  const int r0g = g0 >> 3, c0g = g0 & 7;
  const int r1g = g1 >> 3, c1g = g1 & 7;
  const int ksrc0 = r0g * Hn + ((c0g ^ (r0g & 7)) << 3);
  const int ksrc1 = r1g * Hn + ((c1g ^ (r1g & 7)) << 3);
  const int wb0 = w * 64 * 8;
  const int wb1 = wb0 + 256 * 8;

  const int vrow = w * 16 + (lane >> 2);
  const int vc   = lane & 3;
  const long vgbase = (long)vrow * Tn + vc * 16;
  const int vs_ = vrow & 7;

  const int swz  = l15 & 7;
  const int cks0 = ((0 * 4 + lh) ^ swz) << 3;
  const int cks1 = ((1 * 4 + lh) ^ swz) << 3;
  const int rfr  = l15 * 64;

  int cur = 0;

  {
    const u16* kt = kb_g + (long)it0 * 64 * Hn;
    gl16(kt + ksrc0, &kbuf[0][wb0]);
    gl16(kt + ksrc1, &kbuf[0][wb1]);
    const short8 v0 = *reinterpret_cast<const short8*>(vb_g + vgbase + it0 * 64);
    const short8 v1 = *reinterpret_cast<const short8*>(vb_g + vgbase + it0 * 64 + 8);
    u16* vdst = &vbuf[0][0] + vrow * 64;
    const int gb = (vc >> 1) * 4, off8 = (vc & 1) * 4;
    *reinterpret_cast<short4v*>(vdst + (((gb + 0) ^ vs_) << 3) + off8) = short4v{v0[0], v0[1], v0[2], v0[3]};
    *reinterpret_cast<short4v*>(vdst + (((gb + 1) ^ vs_) << 3) + off8) = short4v{v0[4], v0[5], v0[6], v0[7]};
    *reinterpret_cast<short4v*>(vdst + (((gb + 2) ^ vs_) << 3) + off8) = short4v{v1[0], v1[1], v1[2], v1[3]};
    *reinterpret_cast<short4v*>(vdst + (((gb + 3) ^ vs_) << 3) + off8) = short4v{v1[4], v1[5], v1[6], v1[7]};
  }
  __syncthreads();

  for (int it = it0; it < it1; ++it) {
    short8 nv0, nv1;
    const bool pf = (it + 1 < it1);
    if (pf) {
      const u16* kt = kb_g + (long)(it + 1) * 64 * Hn;
      gl16(kt + ksrc0, &kbuf[cur ^ 1][wb0]);
      gl16(kt + ksrc1, &kbuf[cur ^ 1][wb1]);
      nv0 = *reinterpret_cast<const short8*>(vb_g + vgbase + (it + 1) * 64);
      nv1 = *reinterpret_cast<const short8*>(vb_g + vgbase + (it + 1) * 64 + 8);
    }

    const u16* kc  = &kbuf[cur][0];
    const u16* vcb = &vbuf[cur][0];

    f32x4 s[4];
    #pragma unroll
    for (int n = 0; n < 4; ++n) s[n] = f32x4{0.f, 0.f, 0.f, 0.f};
    #pragma unroll
    for (int n = 0; n < 4; ++n) {
      const short8 ak0 = *reinterpret_cast<const short8*>(&kc[n * 1024 + rfr + cks0]);
      s[n] = MFMA16(ak0, aq[0], s[n]);
      const short8 ak1 = *reinterpret_cast<const short8*>(&kc[n * 1024 + rfr + cks1]);
      s[n] = MFMA16(ak1, aq[1], s[n]);
    }

    #pragma unroll
    for (int n = 0; n < 4; ++n)
      #pragma unroll
      for (int r = 0; r < 4; ++r)
        s[n][r] = __builtin_amdgcn_exp2f(s[n][r]);

    {
      float t0 = (s[0][0] + s[0][1]) + (s[0][2] + s[0][3]);
      float t1 = (s[1][0] + s[1][1]) + (s[1][2] + s[1][3]);
      float t2 = (s[2][0] + s[2][1]) + (s[2][2] + s[2][3]);
      float t3 = (s[3][0] + s[3][1]) + (s[3][2] + s[3][3]);
      lacc += (t0 + t1) + (t2 + t3);
    }

    union { short8 s8; uint32_t u[4]; } B0, B1;
    B0.u[0] = pkbf(s[0][0], s[0][1]); B0.u[1] = pkbf(s[0][2], s[0][3]);
    B0.u[2] = pkbf(s[1][0], s[1][1]); B0.u[3] = pkbf(s[1][2], s[1][3]);
    B1.u[0] = pkbf(s[2][0], s[2][1]); B1.u[1] = pkbf(s[2][2], s[2][3]);
    B1.u[2] = pkbf(s[3][0], s[3][1]); B1.u[3] = pkbf(s[3][2], s[3][3]);

    #pragma unroll
    for (int m = 0; m < 4; ++m) {
      const short8 av0 = *reinterpret_cast<const short8*>(&vcb[m * 1024 + rfr + cks0]);
      o[m] = MFMA16(av0, B0.s8, o[m]);
      const short8 av1 = *reinterpret_cast<const short8*>(&vcb[m * 1024 + rfr + cks1]);
      o[m] = MFMA16(av1, B1.s8, o[m]);
    }

    if (pf) {
      u16* vdst = &vbuf[cur ^ 1][0] + vrow * 64;
      const int gb = (vc >> 1) * 4, off8 = (vc & 1) * 4;
      *reinterpret_cast<short4v*>(vdst + (((gb + 0) ^ vs_) << 3) + off8) = short4v{nv0[0], nv0[1], nv0[2], nv0[3]};
      *reinterpret_cast<short4v*>(vdst + (((gb + 1) ^ vs_) << 3) + off8) = short4v{nv0[4], nv0[5], nv0[6], nv0[7]};
      *reinterpret_cast<short4v*>(vdst + (((gb + 2) ^ vs_) << 3) + off8) = short4v{nv1[0], nv1[1], nv1[2], nv1[3]};
      *reinterpret_cast<short4v*>(vdst + (((gb + 3) ^ vs_) << 3) + off8) = short4v{nv1[4], nv1[5], nv1[6], nv1[7]};
    }

    __syncthreads();
    cur ^= 1;
  }

  float tot = lacc;
  tot += __shfl_xor(tot, 16);
  tot += __shfl_xor(tot, 32);
  const long qrow = rowbase + w * 16 + l15;
  float* od = opart + ((long)split * NELT) + qrow * Hn;
  #pragma unroll
  for (int m = 0; m < 4; ++m) {
    float4 vv;
    vv.x = o[m][0]; vv.y = o[m][1]; vv.z = o[m][2]; vv.w = o[m][3];
    *reinterpret_cast<float4*>(od + m * 16 + lh * 4) = vv;
  }
  if (lh == 0) lpart[(long)split * NTOK + qrow] = tot;
}

// ---------------------------------------------------------------------------
// Kernel 3: combine split-K partials: out = (sum O_s) / (sum l_s)
// ---------------------------------------------------------------------------
__global__ __launch_bounds__(256) void combine(
    const float* __restrict__ op, const float* __restrict__ lp,
    float* __restrict__ out)
{
  const long idx  = (long)blockIdx.x * 256 + threadIdx.x;
  const long base = idx * 4;
  const long row  = base >> 6;
  float4 acc = *reinterpret_cast<const float4*>(op + base);
  float lsum = lp[row];
  #pragma unroll
  for (int s = 1; s < SPLITS; ++s) {
    const float4 c = *reinterpret_cast<const float4*>(op + s * NELT + base);
    acc.x += c.x; acc.y += c.y; acc.z += c.z; acc.w += c.w;
    lsum += lp[s * NTOK + row];
  }
  const float linv = 1.0f / lsum;
  float4 r;
  r.x = acc.x * linv; r.y = acc.y * linv; r.z = acc.z * linv; r.w = acc.w * linv;
  *reinterpret_cast<float4*>(out + base) = r;
}

// ---------------------------------------------------------------------------
extern "C" void kernel_launch(void* const* d_in, const int* in_sizes, int n_in,
                              void* d_out, int out_size, void* d_ws, size_t ws_size,
                              hipStream_t stream) {
  const float* x  = (const float*)d_in[0];
  const float* Wq = (const float*)d_in[1];
  const float* bq = (const float*)d_in[2];
  const float* Wk = (const float*)d_in[3];
  const float* bk = (const float*)d_in[4];
  const float* Wv = (const float*)d_in[5];
  const float* bv = (const float*)d_in[6];
  float* out = (float*)d_out;

  u16* qs  = (u16*)d_ws;                         // [32768][64] bf16, pre-scaled
  u16* ks  = qs + NELT;                          // [32768][64] bf16
  u16* vs  = ks + NELT;                          // V^T [16][64][2048] bf16
  u16* wtd = vs + NELT;                          // WT [3][64][384] bf16
  float* op = (float*)(wtd + 3 * 64 * Cn);       // O partials [SPLITS][32768][64]
  float* lp = op + (long)SPLITS * NELT;          // l partials [SPLITS][32768]

  const int FLASH_BLOCKS = Bn * 32 * SPLITS;     // 2048

  hipLaunchKernelGGL(wtrans, dim3(18), dim3(256), 0, stream, Wq, Wk, Wv, wtd);
  hipLaunchKernelGGL(qkv_proj, dim3((int)(NTOK / 64)), dim3(256), 0, stream,
                     x, wtd, bq, bk, bv, qs, ks, vs);
  hipLaunchKernelGGL(flash_attn, dim3(FLASH_BLOCKS), dim3(256), 0, stream,
                     qs, ks, vs, op, lp);
  hipLaunchKernelGGL(combine, dim3((int)(NELT / 4 / 256)), dim3(256), 0, stream,
                     op, lp, out);
}

// Round 13
// 71.724 us; speedup vs baseline: 1.2063x; 1.0147x over previous
//
#include <hip/hip_runtime.h>
#include <hip/hip_bf16.h>
#include <cstdint>

typedef unsigned short u16;
typedef __attribute__((ext_vector_type(8))) short short8;   // 8 bf16 = 4 VGPR
typedef __attribute__((ext_vector_type(4))) short short4v;  // 4 bf16 = 8B
typedef __attribute__((ext_vector_type(4))) float f32x4;

#define MFMA16(a, b, c) __builtin_amdgcn_mfma_f32_16x16x32_bf16((a), (b), (c), 0, 0, 0)

constexpr int Bn   = 16;
constexpr int Tn   = 2048;
constexpr int Cn   = 384;
constexpr int Hn   = 64;
constexpr int WPAD = 72;                      // 64+8 (2-way LDS reads: free)
constexpr long NTOK = (long)Bn * Tn;          // 32768
constexpr long NELT = NTOK * Hn;              // 2,097,152
constexpr int SPLITS = 4;                     // flash split-K factor
constexpr int NT_PER = 32 / SPLITS;           // KV tiles per block

// Q pre-scale: (1/sqrt(64)) * log2(e), so attention uses bare exp2
#define QSCALE 0.18033688011112042f

// f32 -> bf16 round-to-nearest-even
__device__ __forceinline__ u16 f2bf(float f) {
  union { float f; uint32_t u; } c; c.f = f;
  uint32_t u = c.u;
  return (u16)((u + 0x7fffu + ((u >> 16) & 1u)) >> 16);
}

// pack 2 f32 -> 2 bf16 in one u32 (RNE), gfx950 v_cvt_pk_bf16_f32
__device__ __forceinline__ uint32_t pkbf(float a, float b) {
  uint32_t d;
  asm("v_cvt_pk_bf16_f32 %0, %1, %2" : "=v"(d) : "v"(a), "v"(b));
  return d;
}

// load 8 consecutive f32 and pack to one bf16x8 A-fragment word
__device__ __forceinline__ short8 ldx8(const float* p) {
  const float4 f0 = *reinterpret_cast<const float4*>(p);
  const float4 f1 = *reinterpret_cast<const float4*>(p + 4);
  union { short8 s8; uint32_t u[4]; } r;
  r.u[0] = pkbf(f0.x, f0.y); r.u[1] = pkbf(f0.z, f0.w);
  r.u[2] = pkbf(f1.x, f1.y); r.u[3] = pkbf(f1.z, f1.w);
  return r.s8;
}

// async global->LDS, 16B per lane. LDS dest = wave-uniform base + lane*16.
__device__ __forceinline__ void gl16(const u16* g, const u16* l) {
  __builtin_amdgcn_global_load_lds(
      (const __attribute__((address_space(1))) void*)g,
      (__attribute__((address_space(3))) void*)l, 16, 0, 0);
}

// ---------------------------------------------------------------------------
// Kernel 0: W pre-transpose.  W[384][64] f32 (x3) -> WT[3][64][384] bf16.
// ---------------------------------------------------------------------------
__global__ __launch_bounds__(256) void wtrans(
    const float* __restrict__ Wq, const float* __restrict__ Wk,
    const float* __restrict__ Wv, u16* __restrict__ wtd)
{
  __shared__ u16 tile[64][65];
  const int m  = blockIdx.x / 6;
  const int kc = blockIdx.x % 6;
  const float* W = (m == 0) ? Wq : (m == 1) ? Wk : Wv;
  const int t = threadIdx.x;

  {
    const int kr = t >> 2, seg = t & 3;
    const float* src = W + (size_t)(kc * 64 + kr) * Hn + seg * 16;
    #pragma unroll
    for (int j = 0; j < 4; ++j) {
      const float4 f = *reinterpret_cast<const float4*>(src + j * 4);
      u16* p = &tile[kr][seg * 16 + j * 4];
      p[0] = f2bf(f.x); p[1] = f2bf(f.y); p[2] = f2bf(f.z); p[3] = f2bf(f.w);
    }
  }
  __syncthreads();
  {
    const int hr = t >> 2, seg = t & 3;
    union { short8 s; u16 u[8]; } o0, o1;
    #pragma unroll
    for (int j = 0; j < 8; ++j) o0.u[j] = tile[seg * 16 + j][hr];
    #pragma unroll
    for (int j = 0; j < 8; ++j) o1.u[j] = tile[seg * 16 + 8 + j][hr];
    u16* dst = wtd + ((size_t)m * 64 + hr) * Cn + kc * 64 + seg * 16;
    *reinterpret_cast<short8*>(dst)     = o0.s;
    *reinterpret_cast<short8*>(dst + 8) = o1.s;
  }
}

// ---------------------------------------------------------------------------
// Kernel 1: QKV projection.  W staged in LDS from bf16 WT; x A-frags in a
// 2-stage NAMED-REGISTER pipeline (no runtime-indexed vector arrays -> no
// scratch).  Grid: 512 blocks x 256 thr (4 waves x 16 rows).
// ---------------------------------------------------------------------------
__global__ __launch_bounds__(256) void qkv_proj(
    const float* __restrict__ x, const u16* __restrict__ wtd,
    const float* __restrict__ bq, const float* __restrict__ bk,
    const float* __restrict__ bv,
    u16* __restrict__ oq, u16* __restrict__ ok, u16* __restrict__ ovt)
{
  __shared__ u16 wt[3][Hn * WPAD];   // W k-chunk, transposed [m][h][k] (27.6 KB)

  const int t    = threadIdx.x;
  const int lane = t & 63;
  const int w    = t >> 6;
  const int l15  = lane & 15;
  const int lh   = lane >> 4;
  const long r0  = (long)blockIdx.x * 64;

  const float* xrow = x + (r0 + w * 16 + l15) * Cn;

  // 2-stage x fragment pipeline, all names compile-time
  short8 aCur0 = ldx8(xrow + lh * 8);
  short8 aCur1 = ldx8(xrow + 32 + lh * 8);
  short8 aNxt0, aNxt1;

  f32x4 acc[3][4];
  #pragma unroll
  for (int m = 0; m < 3; ++m)
    #pragma unroll
    for (int n = 0; n < 4; ++n) acc[m][n] = f32x4{0.f, 0.f, 0.f, 0.f};

  for (int kc = 0; kc < 6; ++kc) {
    __syncthreads();   // wt safe to overwrite
    // stage WT chunk: 1536 granules of 16B, coalesced
    #pragma unroll
    for (int i = 0; i < 6; ++i) {
      const int g  = t + i * 256;
      const int c8 = g & 7, h = (g >> 3) & 63, m = g >> 9;
      *reinterpret_cast<short8*>(&wt[m][h * WPAD + c8 * 8]) =
          *reinterpret_cast<const short8*>(
              wtd + ((size_t)m * 64 + h) * Cn + kc * 64 + c8 * 8);
    }
    // prefetch next x chunk (hides under W-stage latency + MFMA phase)
    if (kc + 1 < 6) {
      const float* p = xrow + (kc + 1) * 64 + lh * 8;
      aNxt0 = ldx8(p);
      aNxt1 = ldx8(p + 32);
    }
    __syncthreads();

    #pragma unroll
    for (int m = 0; m < 3; ++m)
      #pragma unroll
      for (int n = 0; n < 4; ++n) {
        const short8 b0 = *reinterpret_cast<const short8*>(
            &wt[m][(n * 16 + l15) * WPAD + lh * 8]);
        acc[m][n] = MFMA16(aCur0, b0, acc[m][n]);
        const short8 b1 = *reinterpret_cast<const short8*>(
            &wt[m][(n * 16 + l15) * WPAD + 32 + lh * 8]);
        acc[m][n] = MFMA16(aCur1, b1, acc[m][n]);
      }

    aCur0 = aNxt0;
    aCur1 = aNxt1;
  }

  // epilogue: q (scaled) and k row-major
  {
    const float* bias[2] = {bq, bk};
    u16*         dst[2]  = {oq, ok};
    const float  scl[2]  = {QSCALE, 1.0f};
    #pragma unroll
    for (int m = 0; m < 2; ++m) {
      #pragma unroll
      for (int n = 0; n < 4; ++n) {
        int col = n * 16 + l15;
        float bb = bias[m][col];
        #pragma unroll
        for (int r = 0; r < 4; ++r) {
          int row = lh * 4 + r;
          dst[m][(r0 + w * 16 + row) * Hn + col] = f2bf((acc[m][n][r] + bb) * scl[m]);
        }
      }
    }
  }
  // v: TRANSPOSED [b][h][t]
  {
    const long g    = r0 + w * 16 + lh * 4;
    const long bidx = g >> 11;
    const long tloc = g & 2047;
    #pragma unroll
    for (int n = 0; n < 4; ++n) {
      int col = n * 16 + l15;
      float bb = bv[col];
      short4v pk;
      #pragma unroll
      for (int r = 0; r < 4; ++r) pk[r] = (short)f2bf(acc[2][n][r] + bb);
      *reinterpret_cast<short4v*>(ovt + (bidx * Hn + col) * Tn + tloc) = pk;
    }
  }
}

// ---------------------------------------------------------------------------
// Kernel 2: flash attention, swapped-QK in-register softmax, SPLIT-K x4.
// (byte-identical to R12)
// ---------------------------------------------------------------------------
__global__ __launch_bounds__(256) void flash_attn(
    const u16* __restrict__ q, const u16* __restrict__ k,
    const u16* __restrict__ vt, float* __restrict__ opart,
    float* __restrict__ lpart)
{
  __shared__ u16 kbuf[2][64 * 64];
  __shared__ u16 vbuf[2][64 * 64];

  const int t    = threadIdx.x;
  const int lane = t & 63;
  const int w    = t >> 6;
  const int l15  = lane & 15;
  const int lh   = lane >> 4;
  const int swz_id = ((blockIdx.x & 7) << 8) | (blockIdx.x >> 3);
  const int qt    = swz_id & 31;
  const int split = (swz_id >> 5) & (SPLITS - 1);
  const int b     = swz_id >> 7;
  const long rowbase = (long)b * Tn + qt * 64;
  const int it0 = split * NT_PER, it1 = it0 + NT_PER;

  short8 aq[2];
  {
    const u16* qrow = q + (rowbase + w * 16 + l15) * Hn;
    aq[0] = *reinterpret_cast<const short8*>(qrow + lh * 8);
    aq[1] = *reinterpret_cast<const short8*>(qrow + 32 + lh * 8);
  }

  f32x4 o[4];
  #pragma unroll
  for (int m = 0; m < 4; ++m) o[m] = f32x4{0.f, 0.f, 0.f, 0.f};
  float lacc = 0.f;

  const u16* kb_g = k  + (long)b * Tn * Hn;
  const u16* vb_g = vt + (long)b * Hn * Tn;

  const int g0 = t, g1 = 256 + t;
  const int r0g = g0 >> 3, c0g = g0 & 7;
  const int r1g = g1 >> 3, c1g = g1 & 7;
  const int ksrc0 = r0g * Hn + ((c0g ^ (r0g & 7)) << 3);
  const int ksrc1 = r1g * Hn + ((c1g ^ (r1g & 7)) << 3);
  const int wb0 = w * 64 * 8;
  const int wb1 = wb0 + 256 * 8;

  const int vrow = w * 16 + (lane >> 2);
  const int vc   = lane & 3;
  const long vgbase = (long)vrow * Tn + vc * 16;
  const int vs_ = vrow & 7;

  const int swz  = l15 & 7;
  const int cks0 = ((0 * 4 + lh) ^ swz) << 3;
  const int cks1 = ((1 * 4 + lh) ^ swz) << 3;
  const int rfr  = l15 * 64;

  int cur = 0;

  {
    const u16* kt = kb_g + (long)it0 * 64 * Hn;
    gl16(kt + ksrc0, &kbuf[0][wb0]);
    gl16(kt + ksrc1, &kbuf[0][wb1]);
    const short8 v0 = *reinterpret_cast<const short8*>(vb_g + vgbase + it0 * 64);
    const short8 v1 = *reinterpret_cast<const short8*>(vb_g + vgbase + it0 * 64 + 8);
    u16* vdst = &vbuf[0][0] + vrow * 64;
    const int gb = (vc >> 1) * 4, off8 = (vc & 1) * 4;
    *reinterpret_cast<short4v*>(vdst + (((gb + 0) ^ vs_) << 3) + off8) = short4v{v0[0], v0[1], v0[2], v0[3]};
    *reinterpret_cast<short4v*>(vdst + (((gb + 1) ^ vs_) << 3) + off8) = short4v{v0[4], v0[5], v0[6], v0[7]};
    *reinterpret_cast<short4v*>(vdst + (((gb + 2) ^ vs_) << 3) + off8) = short4v{v1[0], v1[1], v1[2], v1[3]};
    *reinterpret_cast<short4v*>(vdst + (((gb + 3) ^ vs_) << 3) + off8) = short4v{v1[4], v1[5], v1[6], v1[7]};
  }
  __syncthreads();

  for (int it = it0; it < it1; ++it) {
    short8 nv0, nv1;
    const bool pf = (it + 1 < it1);
    if (pf) {
      const u16* kt = kb_g + (long)(it + 1) * 64 * Hn;
      gl16(kt + ksrc0, &kbuf[cur ^ 1][wb0]);
      gl16(kt + ksrc1, &kbuf[cur ^ 1][wb1]);
      nv0 = *reinterpret_cast<const short8*>(vb_g + vgbase + (it + 1) * 64);
      nv1 = *reinterpret_cast<const short8*>(vb_g + vgbase + (it + 1) * 64 + 8);
    }

    const u16* kc  = &kbuf[cur][0];
    const u16* vcb = &vbuf[cur][0];

    f32x4 s[4];
    #pragma unroll
    for (int n = 0; n < 4; ++n) s[n] = f32x4{0.f, 0.f, 0.f, 0.f};
    #pragma unroll
    for (int n = 0; n < 4; ++n) {
      const short8 ak0 = *reinterpret_cast<const short8*>(&kc[n * 1024 + rfr + cks0]);
      s[n] = MFMA16(ak0, aq[0], s[n]);
      const short8 ak1 = *reinterpret_cast<const short8*>(&kc[n * 1024 + rfr + cks1]);
      s[n] = MFMA16(ak1, aq[1], s[n]);
    }

    #pragma unroll
    for (int n = 0; n < 4; ++n)
      #pragma unroll
      for (int r = 0; r < 4; ++r)
        s[n][r] = __builtin_amdgcn_exp2f(s[n][r]);

    {
      float t0 = (s[0][0] + s[0][1]) + (s[0][2] + s[0][3]);
      float t1 = (s[1][0] + s[1][1]) + (s[1][2] + s[1][3]);
      float t2 = (s[2][0] + s[2][1]) + (s[2][2] + s[2][3]);
      float t3 = (s[3][0] + s[3][1]) + (s[3][2] + s[3][3]);
      lacc += (t0 + t1) + (t2 + t3);
    }

    union { short8 s8; uint32_t u[4]; } B0, B1;
    B0.u[0] = pkbf(s[0][0], s[0][1]); B0.u[1] = pkbf(s[0][2], s[0][3]);
    B0.u[2] = pkbf(s[1][0], s[1][1]); B0.u[3] = pkbf(s[1][2], s[1][3]);
    B1.u[0] = pkbf(s[2][0], s[2][1]); B1.u[1] = pkbf(s[2][2], s[2][3]);
    B1.u[2] = pkbf(s[3][0], s[3][1]); B1.u[3] = pkbf(s[3][2], s[3][3]);

    #pragma unroll
    for (int m = 0; m < 4; ++m) {
      const short8 av0 = *reinterpret_cast<const short8*>(&vcb[m * 1024 + rfr + cks0]);
      o[m] = MFMA16(av0, B0.s8, o[m]);
      const short8 av1 = *reinterpret_cast<const short8*>(&vcb[m * 1024 + rfr + cks1]);
      o[m] = MFMA16(av1, B1.s8, o[m]);
    }

    if (pf) {
      u16* vdst = &vbuf[cur ^ 1][0] + vrow * 64;
      const int gb = (vc >> 1) * 4, off8 = (vc & 1) * 4;
      *reinterpret_cast<short4v*>(vdst + (((gb + 0) ^ vs_) << 3) + off8) = short4v{nv0[0], nv0[1], nv0[2], nv0[3]};
      *reinterpret_cast<short4v*>(vdst + (((gb + 1) ^ vs_) << 3) + off8) = short4v{nv0[4], nv0[5], nv0[6], nv0[7]};
      *reinterpret_cast<short4v*>(vdst + (((gb + 2) ^ vs_) << 3) + off8) = short4v{nv1[0], nv1[1], nv1[2], nv1[3]};
      *reinterpret_cast<short4v*>(vdst + (((gb + 3) ^ vs_) << 3) + off8) = short4v{nv1[4], nv1[5], nv1[6], nv1[7]};
    }

    __syncthreads();
    cur ^= 1;
  }

  float tot = lacc;
  tot += __shfl_xor(tot, 16);
  tot += __shfl_xor(tot, 32);
  const long qrow = rowbase + w * 16 + l15;
  float* od = opart + ((long)split * NELT) + qrow * Hn;
  #pragma unroll
  for (int m = 0; m < 4; ++m) {
    float4 vv;
    vv.x = o[m][0]; vv.y = o[m][1]; vv.z = o[m][2]; vv.w = o[m][3];
    *reinterpret_cast<float4*>(od + m * 16 + lh * 4) = vv;
  }
  if (lh == 0) lpart[(long)split * NTOK + qrow] = tot;
}

// ---------------------------------------------------------------------------
// Kernel 3: combine split-K partials: out = (sum O_s) / (sum l_s)
// ---------------------------------------------------------------------------
__global__ __launch_bounds__(256) void combine(
    const float* __restrict__ op, const float* __restrict__ lp,
    float* __restrict__ out)
{
  const long idx  = (long)blockIdx.x * 256 + threadIdx.x;
  const long base = idx * 4;
  const long row  = base >> 6;
  float4 acc = *reinterpret_cast<const float4*>(op + base);
  float lsum = lp[row];
  #pragma unroll
  for (int s = 1; s < SPLITS; ++s) {
    const float4 c = *reinterpret_cast<const float4*>(op + s * NELT + base);
    acc.x += c.x; acc.y += c.y; acc.z += c.z; acc.w += c.w;
    lsum += lp[s * NTOK + row];
  }
  const float linv = 1.0f / lsum;
  float4 r;
  r.x = acc.x * linv; r.y = acc.y * linv; r.z = acc.z * linv; r.w = acc.w * linv;
  *reinterpret_cast<float4*>(out + base) = r;
}

// ---------------------------------------------------------------------------
extern "C" void kernel_launch(void* const* d_in, const int* in_sizes, int n_in,
                              void* d_out, int out_size, void* d_ws, size_t ws_size,
                              hipStream_t stream) {
  const float* x  = (const float*)d_in[0];
  const float* Wq = (const float*)d_in[1];
  const float* bq = (const float*)d_in[2];
  const float* Wk = (const float*)d_in[3];
  const float* bk = (const float*)d_in[4];
  const float* Wv = (const float*)d_in[5];
  const float* bv = (const float*)d_in[6];
  float* out = (float*)d_out;

  u16* qs  = (u16*)d_ws;                         // [32768][64] bf16, pre-scaled
  u16* ks  = qs + NELT;                          // [32768][64] bf16
  u16* vs  = ks + NELT;                          // V^T [16][64][2048] bf16
  u16* wtd = vs + NELT;                          // WT [3][64][384] bf16
  float* op = (float*)(wtd + 3 * 64 * Cn);       // O partials [SPLITS][32768][64]
  float* lp = op + (long)SPLITS * NELT;          // l partials [SPLITS][32768]

  const int FLASH_BLOCKS = Bn * 32 * SPLITS;     // 2048

  hipLaunchKernelGGL(wtrans, dim3(18), dim3(256), 0, stream, Wq, Wk, Wv, wtd);
  hipLaunchKernelGGL(qkv_proj, dim3((int)(NTOK / 64)), dim3(256), 0, stream,
                     x, wtd, bq, bk, bv, qs, ks, vs);
  hipLaunchKernelGGL(flash_attn, dim3(FLASH_BLOCKS), dim3(256), 0, stream,
                     qs, ks, vs, op, lp);
  hipLaunchKernelGGL(combine, dim3((int)(NELT / 4 / 256)), dim3(256), 0, stream,
                     op, lp, out);
}

// Round 14
// 63.012 us; speedup vs baseline: 1.3731x; 1.1383x over previous
//
#include <hip/hip_runtime.h>
#include <hip/hip_bf16.h>
#include <cstdint>

typedef unsigned short u16;
typedef __attribute__((ext_vector_type(8))) short short8;   // 8 bf16 = 4 VGPR
typedef __attribute__((ext_vector_type(4))) short short4v;  // 4 bf16 = 8B
typedef __attribute__((ext_vector_type(4))) float f32x4;

#define MFMA16(a, b, c) __builtin_amdgcn_mfma_f32_16x16x32_bf16((a), (b), (c), 0, 0, 0)

constexpr int Bn   = 16;
constexpr int Tn   = 2048;
constexpr int Cn   = 384;
constexpr int Hn   = 64;
constexpr long NTOK = (long)Bn * Tn;          // 32768
constexpr long NELT = NTOK * Hn;              // 2,097,152
constexpr int SPLITS = 4;                     // flash split-K factor
constexpr int NT_PER = 32 / SPLITS;           // KV tiles per block

// Q pre-scale: (1/sqrt(64)) * log2(e), so attention uses bare exp2
#define QSCALE 0.18033688011112042f

// f32 -> bf16 round-to-nearest-even
__device__ __forceinline__ u16 f2bf(float f) {
  union { float f; uint32_t u; } c; c.f = f;
  uint32_t u = c.u;
  return (u16)((u + 0x7fffu + ((u >> 16) & 1u)) >> 16);
}

// pack 2 f32 -> 2 bf16 in one u32 (RNE), gfx950 v_cvt_pk_bf16_f32
__device__ __forceinline__ uint32_t pkbf(float a, float b) {
  uint32_t d;
  asm("v_cvt_pk_bf16_f32 %0, %1, %2" : "=v"(d) : "v"(a), "v"(b));
  return d;
}

// load 8 consecutive f32 and pack to one bf16x8 A-fragment word
__device__ __forceinline__ short8 ldx8(const float* p) {
  const float4 f0 = *reinterpret_cast<const float4*>(p);
  const float4 f1 = *reinterpret_cast<const float4*>(p + 4);
  union { short8 s8; uint32_t u[4]; } r;
  r.u[0] = pkbf(f0.x, f0.y); r.u[1] = pkbf(f0.z, f0.w);
  r.u[2] = pkbf(f1.x, f1.y); r.u[3] = pkbf(f1.z, f1.w);
  return r.s8;
}

// async global->LDS, 16B per lane. LDS dest = wave-uniform base + lane*16.
__device__ __forceinline__ void gl16(const u16* g, const u16* l) {
  __builtin_amdgcn_global_load_lds(
      (const __attribute__((address_space(1))) void*)g,
      (__attribute__((address_space(3))) void*)l, 16, 0, 0);
}

// ---------------------------------------------------------------------------
// Kernel 0: W pre-transpose.  W[384][64] f32 (x3) -> WT[3][64][384] bf16.
// ---------------------------------------------------------------------------
__global__ __launch_bounds__(256) void wtrans(
    const float* __restrict__ Wq, const float* __restrict__ Wk,
    const float* __restrict__ Wv, u16* __restrict__ wtd)
{
  __shared__ u16 tile[64][65];
  const int m  = blockIdx.x / 6;
  const int kc = blockIdx.x % 6;
  const float* W = (m == 0) ? Wq : (m == 1) ? Wk : Wv;
  const int t = threadIdx.x;

  {
    const int kr = t >> 2, seg = t & 3;
    const float* src = W + (size_t)(kc * 64 + kr) * Hn + seg * 16;
    #pragma unroll
    for (int j = 0; j < 4; ++j) {
      const float4 f = *reinterpret_cast<const float4*>(src + j * 4);
      u16* p = &tile[kr][seg * 16 + j * 4];
      p[0] = f2bf(f.x); p[1] = f2bf(f.y); p[2] = f2bf(f.z); p[3] = f2bf(f.w);
    }
  }
  __syncthreads();
  {
    const int hr = t >> 2, seg = t & 3;
    union { short8 s; u16 u[8]; } o0, o1;
    #pragma unroll
    for (int j = 0; j < 8; ++j) o0.u[j] = tile[seg * 16 + j][hr];
    #pragma unroll
    for (int j = 0; j < 8; ++j) o1.u[j] = tile[seg * 16 + 8 + j][hr];
    u16* dst = wtd + ((size_t)m * 64 + hr) * Cn + kc * 64 + seg * 16;
    *reinterpret_cast<short8*>(dst)     = o0.s;
    *reinterpret_cast<short8*>(dst + 8) = o1.s;
  }
}

// ---------------------------------------------------------------------------
// Kernel 1: QKV projection.  W k-chunks staged DOUBLE-BUFFERED via
// global_load_lds with granule-XOR swizzle (flash pattern: linear LDS dest,
// inverse-swizzled global source, same XOR on ds_read).  x A-frags in named
// registers.  One barrier per kc; staging latency hides under MFMA phase.
// Grid: 512 blocks x 256 thr (4 waves x 16 rows); LDS 48 KB.
// ---------------------------------------------------------------------------
__global__ __launch_bounds__(256) void qkv_proj(
    const float* __restrict__ x, const u16* __restrict__ wtd,
    const float* __restrict__ bq, const float* __restrict__ bk,
    const float* __restrict__ bv,
    u16* __restrict__ oq, u16* __restrict__ ok, u16* __restrict__ ovt)
{
  __shared__ u16 wbuf[2][3 * 64 * 64];   // 24 KB per buffer, swizzled granules

  const int t    = threadIdx.x;
  const int lane = t & 63;
  const int w    = t >> 6;
  const int l15  = lane & 15;
  const int lh   = lane >> 4;
  const long r0  = (long)blockIdx.x * 64;

  // staging geometry: chunk = 192 rows (m*64+h) x 8 granules of 16B.
  // thread t, pass i -> granule g = i*256 + t; LDS slot g holds global
  // granule (r, c ^ (r&7)) where r=g>>3, c=g&7.
  int srcoff[6];
  #pragma unroll
  for (int i = 0; i < 6; ++i) {
    const int g = i * 256 + t;
    const int r = g >> 3, c = g & 7;
    srcoff[i] = r * Cn + ((c ^ (r & 7)) << 3);
  }
  const int ldsb = w * 64 * 8;   // wave-uniform: wave w covers granules [w*64, w*64+64) per pass

  const float* xrow = x + (r0 + w * 16 + l15) * Cn;

  // x fragment pipeline, named registers
  short8 aCur0 = ldx8(xrow + lh * 8);
  short8 aCur1 = ldx8(xrow + 32 + lh * 8);
  short8 aNxt0, aNxt1;

  // fragment-read swizzle (identical to flash): row group l15, granule ^= l15&7
  const int cks0 = ((lh)     ^ (l15 & 7)) << 3;
  const int cks1 = ((lh + 4) ^ (l15 & 7)) << 3;

  f32x4 acc[3][4];
  #pragma unroll
  for (int m = 0; m < 3; ++m)
    #pragma unroll
    for (int n = 0; n < 4; ++n) acc[m][n] = f32x4{0.f, 0.f, 0.f, 0.f};

  // prologue: stage chunk 0
  #pragma unroll
  for (int i = 0; i < 6; ++i)
    gl16(wtd + srcoff[i], &wbuf[0][(i * 256) * 8 + ldsb]);
  __syncthreads();

  int cur = 0;
  for (int kc = 0; kc < 6; ++kc) {
    if (kc + 1 < 6) {
      // async-stage next chunk + prefetch next x (in flight across MFMAs)
      #pragma unroll
      for (int i = 0; i < 6; ++i)
        gl16(wtd + (kc + 1) * 64 + srcoff[i], &wbuf[cur ^ 1][(i * 256) * 8 + ldsb]);
      const float* p = xrow + (kc + 1) * 64 + lh * 8;
      aNxt0 = ldx8(p);
      aNxt1 = ldx8(p + 32);
    }

    const u16* wc = &wbuf[cur][0];
    #pragma unroll
    for (int m = 0; m < 3; ++m)
      #pragma unroll
      for (int n = 0; n < 4; ++n) {
        const int row = m * 64 + n * 16 + l15;
        const short8 b0 = *reinterpret_cast<const short8*>(&wc[row * 64 + cks0]);
        acc[m][n] = MFMA16(aCur0, b0, acc[m][n]);
        const short8 b1 = *reinterpret_cast<const short8*>(&wc[row * 64 + cks1]);
        acc[m][n] = MFMA16(aCur1, b1, acc[m][n]);
      }

    __syncthreads();   // drains gl16 for cur^1; protects cur before overwrite
    aCur0 = aNxt0;
    aCur1 = aNxt1;
    cur ^= 1;
  }

  // epilogue: q (scaled) and k row-major
  {
    const float* bias[2] = {bq, bk};
    u16*         dst[2]  = {oq, ok};
    const float  scl[2]  = {QSCALE, 1.0f};
    #pragma unroll
    for (int m = 0; m < 2; ++m) {
      #pragma unroll
      for (int n = 0; n < 4; ++n) {
        int col = n * 16 + l15;
        float bb = bias[m][col];
        #pragma unroll
        for (int r = 0; r < 4; ++r) {
          int row = lh * 4 + r;
          dst[m][(r0 + w * 16 + row) * Hn + col] = f2bf((acc[m][n][r] + bb) * scl[m]);
        }
      }
    }
  }
  // v: TRANSPOSED [b][h][t]
  {
    const long g    = r0 + w * 16 + lh * 4;
    const long bidx = g >> 11;
    const long tloc = g & 2047;
    #pragma unroll
    for (int n = 0; n < 4; ++n) {
      int col = n * 16 + l15;
      float bb = bv[col];
      short4v pk;
      #pragma unroll
      for (int r = 0; r < 4; ++r) pk[r] = (short)f2bf(acc[2][n][r] + bb);
      *reinterpret_cast<short4v*>(ovt + (bidx * Hn + col) * Tn + tloc) = pk;
    }
  }
}

// ---------------------------------------------------------------------------
// Kernel 2: flash attention, swapped-QK in-register softmax, SPLIT-K x4.
// (byte-identical to R13)
// ---------------------------------------------------------------------------
__global__ __launch_bounds__(256) void flash_attn(
    const u16* __restrict__ q, const u16* __restrict__ k,
    const u16* __restrict__ vt, float* __restrict__ opart,
    float* __restrict__ lpart)
{
  __shared__ u16 kbuf[2][64 * 64];
  __shared__ u16 vbuf[2][64 * 64];

  const int t    = threadIdx.x;
  const int lane = t & 63;
  const int w    = t >> 6;
  const int l15  = lane & 15;
  const int lh   = lane >> 4;
  const int swz_id = ((blockIdx.x & 7) << 8) | (blockIdx.x >> 3);
  const int qt    = swz_id & 31;
  const int split = (swz_id >> 5) & (SPLITS - 1);
  const int b     = swz_id >> 7;
  const long rowbase = (long)b * Tn + qt * 64;
  const int it0 = split * NT_PER, it1 = it0 + NT_PER;

  short8 aq[2];
  {
    const u16* qrow = q + (rowbase + w * 16 + l15) * Hn;
    aq[0] = *reinterpret_cast<const short8*>(qrow + lh * 8);
    aq[1] = *reinterpret_cast<const short8*>(qrow + 32 + lh * 8);
  }

  f32x4 o[4];
  #pragma unroll
  for (int m = 0; m < 4; ++m) o[m] = f32x4{0.f, 0.f, 0.f, 0.f};
  float lacc = 0.f;

  const u16* kb_g = k  + (long)b * Tn * Hn;
  const u16* vb_g = vt + (long)b * Hn * Tn;

  const int g0 = t, g1 = 256 + t;
  const int r0g = g0 >> 3, c0g = g0 & 7;
  const int r1g = g1 >> 3, c1g = g1 & 7;
  const int ksrc0 = r0g * Hn + ((c0g ^ (r0g & 7)) << 3);
  const int ksrc1 = r1g * Hn + ((c1g ^ (r1g & 7)) << 3);
  const int wb0 = w * 64 * 8;
  const int wb1 = wb0 + 256 * 8;

  const int vrow = w * 16 + (lane >> 2);
  const int vc   = lane & 3;
  const long vgbase = (long)vrow * Tn + vc * 16;
  const int vs_ = vrow & 7;

  const int swz  = l15 & 7;
  const int cks0 = ((0 * 4 + lh) ^ swz) << 3;
  const int cks1 = ((1 * 4 + lh) ^ swz) << 3;
  const int rfr  = l15 * 64;

  int cur = 0;

  {
    const u16* kt = kb_g + (long)it0 * 64 * Hn;
    gl16(kt + ksrc0, &kbuf[0][wb0]);
    gl16(kt + ksrc1, &kbuf[0][wb1]);
    const short8 v0 = *reinterpret_cast<const short8*>(vb_g + vgbase + it0 * 64);
    const short8 v1 = *reinterpret_cast<const short8*>(vb_g + vgbase + it0 * 64 + 8);
    u16* vdst = &vbuf[0][0] + vrow * 64;
    const int gb = (vc >> 1) * 4, off8 = (vc & 1) * 4;
    *reinterpret_cast<short4v*>(vdst + (((gb + 0) ^ vs_) << 3) + off8) = short4v{v0[0], v0[1], v0[2], v0[3]};
    *reinterpret_cast<short4v*>(vdst + (((gb + 1) ^ vs_) << 3) + off8) = short4v{v0[4], v0[5], v0[6], v0[7]};
    *reinterpret_cast<short4v*>(vdst + (((gb + 2) ^ vs_) << 3) + off8) = short4v{v1[0], v1[1], v1[2], v1[3]};
    *reinterpret_cast<short4v*>(vdst + (((gb + 3) ^ vs_) << 3) + off8) = short4v{v1[4], v1[5], v1[6], v1[7]};
  }
  __syncthreads();

  for (int it = it0; it < it1; ++it) {
    short8 nv0, nv1;
    const bool pf = (it + 1 < it1);
    if (pf) {
      const u16* kt = kb_g + (long)(it + 1) * 64 * Hn;
      gl16(kt + ksrc0, &kbuf[cur ^ 1][wb0]);
      gl16(kt + ksrc1, &kbuf[cur ^ 1][wb1]);
      nv0 = *reinterpret_cast<const short8*>(vb_g + vgbase + (it + 1) * 64);
      nv1 = *reinterpret_cast<const short8*>(vb_g + vgbase + (it + 1) * 64 + 8);
    }

    const u16* kc  = &kbuf[cur][0];
    const u16* vcb = &vbuf[cur][0];

    f32x4 s[4];
    #pragma unroll
    for (int n = 0; n < 4; ++n) s[n] = f32x4{0.f, 0.f, 0.f, 0.f};
    #pragma unroll
    for (int n = 0; n < 4; ++n) {
      const short8 ak0 = *reinterpret_cast<const short8*>(&kc[n * 1024 + rfr + cks0]);
      s[n] = MFMA16(ak0, aq[0], s[n]);
      const short8 ak1 = *reinterpret_cast<const short8*>(&kc[n * 1024 + rfr + cks1]);
      s[n] = MFMA16(ak1, aq[1], s[n]);
    }

    #pragma unroll
    for (int n = 0; n < 4; ++n)
      #pragma unroll
      for (int r = 0; r < 4; ++r)
        s[n][r] = __builtin_amdgcn_exp2f(s[n][r]);

    {
      float t0 = (s[0][0] + s[0][1]) + (s[0][2] + s[0][3]);
      float t1 = (s[1][0] + s[1][1]) + (s[1][2] + s[1][3]);
      float t2 = (s[2][0] + s[2][1]) + (s[2][2] + s[2][3]);
      float t3 = (s[3][0] + s[3][1]) + (s[3][2] + s[3][3]);
      lacc += (t0 + t1) + (t2 + t3);
    }

    union { short8 s8; uint32_t u[4]; } B0, B1;
    B0.u[0] = pkbf(s[0][0], s[0][1]); B0.u[1] = pkbf(s[0][2], s[0][3]);
    B0.u[2] = pkbf(s[1][0], s[1][1]); B0.u[3] = pkbf(s[1][2], s[1][3]);
    B1.u[0] = pkbf(s[2][0], s[2][1]); B1.u[1] = pkbf(s[2][2], s[2][3]);
    B1.u[2] = pkbf(s[3][0], s[3][1]); B1.u[3] = pkbf(s[3][2], s[3][3]);

    #pragma unroll
    for (int m = 0; m < 4; ++m) {
      const short8 av0 = *reinterpret_cast<const short8*>(&vcb[m * 1024 + rfr + cks0]);
      o[m] = MFMA16(av0, B0.s8, o[m]);
      const short8 av1 = *reinterpret_cast<const short8*>(&vcb[m * 1024 + rfr + cks1]);
      o[m] = MFMA16(av1, B1.s8, o[m]);
    }

    if (pf) {
      u16* vdst = &vbuf[cur ^ 1][0] + vrow * 64;
      const int gb = (vc >> 1) * 4, off8 = (vc & 1) * 4;
      *reinterpret_cast<short4v*>(vdst + (((gb + 0) ^ vs_) << 3) + off8) = short4v{nv0[0], nv0[1], nv0[2], nv0[3]};
      *reinterpret_cast<short4v*>(vdst + (((gb + 1) ^ vs_) << 3) + off8) = short4v{nv0[4], nv0[5], nv0[6], nv0[7]};
      *reinterpret_cast<short4v*>(vdst + (((gb + 2) ^ vs_) << 3) + off8) = short4v{nv1[0], nv1[1], nv1[2], nv1[3]};
      *reinterpret_cast<short4v*>(vdst + (((gb + 3) ^ vs_) << 3) + off8) = short4v{nv1[4], nv1[5], nv1[6], nv1[7]};
    }

    __syncthreads();
    cur ^= 1;
  }

  float tot = lacc;
  tot += __shfl_xor(tot, 16);
  tot += __shfl_xor(tot, 32);
  const long qrow = rowbase + w * 16 + l15;
  float* od = opart + ((long)split * NELT) + qrow * Hn;
  #pragma unroll
  for (int m = 0; m < 4; ++m) {
    float4 vv;
    vv.x = o[m][0]; vv.y = o[m][1]; vv.z = o[m][2]; vv.w = o[m][3];
    *reinterpret_cast<float4*>(od + m * 16 + lh * 4) = vv;
  }
  if (lh == 0) lpart[(long)split * NTOK + qrow] = tot;
}

// ---------------------------------------------------------------------------
// Kernel 3: combine split-K partials: out = (sum O_s) / (sum l_s)
// ---------------------------------------------------------------------------
__global__ __launch_bounds__(256) void combine(
    const float* __restrict__ op, const float* __restrict__ lp,
    float* __restrict__ out)
{
  const long idx  = (long)blockIdx.x * 256 + threadIdx.x;
  const long base = idx * 4;
  const long row  = base >> 6;
  float4 acc = *reinterpret_cast<const float4*>(op + base);
  float lsum = lp[row];
  #pragma unroll
  for (int s = 1; s < SPLITS; ++s) {
    const float4 c = *reinterpret_cast<const float4*>(op + s * NELT + base);
    acc.x += c.x; acc.y += c.y; acc.z += c.z; acc.w += c.w;
    lsum += lp[s * NTOK + row];
  }
  const float linv = 1.0f / lsum;
  float4 r;
  r.x = acc.x * linv; r.y = acc.y * linv; r.z = acc.z * linv; r.w = acc.w * linv;
  *reinterpret_cast<float4*>(out + base) = r;
}

// ---------------------------------------------------------------------------
extern "C" void kernel_launch(void* const* d_in, const int* in_sizes, int n_in,
                              void* d_out, int out_size, void* d_ws, size_t ws_size,
                              hipStream_t stream) {
  const float* x  = (const float*)d_in[0];
  const float* Wq = (const float*)d_in[1];
  const float* bq = (const float*)d_in[2];
  const float* Wk = (const float*)d_in[3];
  const float* bk = (const float*)d_in[4];
  const float* Wv = (const float*)d_in[5];
  const float* bv = (const float*)d_in[6];
  float* out = (float*)d_out;

  u16* qs  = (u16*)d_ws;                         // [32768][64] bf16, pre-scaled
  u16* ks  = qs + NELT;                          // [32768][64] bf16
  u16* vs  = ks + NELT;                          // V^T [16][64][2048] bf16
  u16* wtd = vs + NELT;                          // WT [3][64][384] bf16
  float* op = (float*)(wtd + 3 * 64 * Cn);       // O partials [SPLITS][32768][64]
  float* lp = op + (long)SPLITS * NELT;          // l partials [SPLITS][32768]

  const int FLASH_BLOCKS = Bn * 32 * SPLITS;     // 2048

  hipLaunchKernelGGL(wtrans, dim3(18), dim3(256), 0, stream, Wq, Wk, Wv, wtd);
  hipLaunchKernelGGL(qkv_proj, dim3((int)(NTOK / 64)), dim3(256), 0, stream,
                     x, wtd, bq, bk, bv, qs, ks, vs);
  hipLaunchKernelGGL(flash_attn, dim3(FLASH_BLOCKS), dim3(256), 0, stream,
                     qs, ks, vs, op, lp);
  hipLaunchKernelGGL(combine, dim3((int)(NELT / 4 / 256)), dim3(256), 0, stream,
                     op, lp, out);
}